// Round 8
// baseline (99.624 us; speedup 1.0000x reference)
//
#include <hip/hip_runtime.h>
#include <math.h>

constexpr int N  = 20000;
constexpr int V  = 6;
constexpr int P  = 64;
constexpr int ND = 32;
constexpr float W_   = 1600.0f;
constexpr float H_   = 928.0f;
constexpr float EPS_ = 1e-5f;

typedef float f32x2 __attribute__((ext_vector_type(2)));

// One wave per EIGHT (n,v) pairs: 4 unrolled independent iterations x
// (lanes 0..31 = pair A depths, lanes 32..63 = pair B depths). The
// iterations share no state (register-only phase 2), so the scheduler
// interleaves iteration k+1's loads/matvec/divides with iteration k's
// butterfly/stores — converting latency exposure into issue (R7 measured
// this lever at ~-3us for 2x; this is the 4x step).
// Phase 1 arithmetic is bit-identical to the passing round-1..7 kernels.
// Phase 2: exact f32 bbox prune (butterfly min/max over valid points, +INF
// sentinels); bbox-inside-ROI => hit, bbox-disjoint => miss, else bit-exact
// readlane fallback over all 32 depths.
__global__ __launch_bounds__(256) void box_corr(
    const float* __restrict__ points,   // N x 3  [img_id, x, y]
    const float* __restrict__ trans,    // V x V x 4 x 4
    const float* __restrict__ rois,     // V x P x 4  [x1,y1,x2,y2]
    float* __restrict__ out_xy,         // N x V x ND x 2
    float* __restrict__ out_mask,       // N x V x ND
    float* __restrict__ out_corr)       // N x V x P
{
    const int tid  = (int)threadIdx.x;
    const int wid  = __builtin_amdgcn_readfirstlane(
                        (int)((blockIdx.x * 256u + tid) >> 6));
    const int lane = tid & 63;

    #pragma unroll
    for (int it = 0; it < 4; ++it) {
        const int gw = wid * 4 + it;           // < 60000 by grid construction

        const int pA = 2 * gw;
        const int pB = pA + 1;
        const int nA = pA / V, vA = pA - nA * V;
        const int nB = pB / V, vB = pB - nB * V;

        const float idA = points[nA * 3 + 0];
        const float xA  = points[nA * 3 + 1];
        const float yA  = points[nA * 3 + 2];
        const float idB = points[nB * 3 + 0];
        const float xB  = points[nB * 3 + 1];
        const float yB  = points[nB * 3 + 2];
        const int imgA = (int)idA;
        const int imgB = (int)idB;
        const int offA = (vA * V + imgA) * 16;
        const int offB = (vB * V + imgB) * 16;

        // Early ROI loads: independent of the matvec/divide chain (L1-hot).
        const float4 ra = ((const float4*)rois)[vA * P + lane];
        const float4 rb = ((const float4*)rois)[vB * P + lane];

        const bool hiHalf = lane >= 32;
        const int  dl     = lane & 31;
        const float x   = hiHalf ? xB : xA;
        const float y   = hiHalf ? yB : yA;
        const int   off = hiHalf ? offB : offA;

        // depths[k] = 0.5 + bin*k*(k+1), left-assoc f32 (matches jnp)
        const float k   = (float)dl;
        const float bin = (float)(69.5 / 1056.0);
        const float d   = __fadd_rn(0.5f, __fmul_rn(__fmul_rn(bin, k), __fadd_rn(k, 1.0f)));

        const float p0 = __fmul_rn(x, d);
        const float p1 = __fmul_rn(y, d);

        const float* T = trans + off;
        const float4 t0 = *(const float4*)(T + 0);
        const float4 t1 = *(const float4*)(T + 4);
        const float4 t2 = *(const float4*)(T + 8);
        // no FMA contraction: match numpy einsum's mul+add sequence
        const float r0 = __fadd_rn(__fadd_rn(__fadd_rn(__fmul_rn(t0.x, p0), __fmul_rn(t0.y, p1)), __fmul_rn(t0.z, d)), t0.w);
        const float r1 = __fadd_rn(__fadd_rn(__fadd_rn(__fmul_rn(t1.x, p0), __fmul_rn(t1.y, p1)), __fmul_rn(t1.z, d)), t1.w);
        const float r2 = __fadd_rn(__fadd_rn(__fadd_rn(__fmul_rn(t2.x, p0), __fmul_rn(t2.y, p1)), __fmul_rn(t2.z, d)), t2.w);

        const float zc = fmaxf(r2, EPS_);
        const float px = r0 / zc;   // IEEE divide — booleans must be exact
        const float py = r1 / zc;
        const bool  ok = (r2 > EPS_) && (px >= 0.0f) && (px < W_) && (py >= 0.0f) && (py < H_);

        // Coalesced streaming stores (gw*64+lane contiguous).
        const size_t base = (size_t)gw * 64 + lane;
        ((f32x2*)out_xy)[base] = (f32x2){ px, py };
        out_mask[base] = ok ? 1.0f : 0.0f;

        const unsigned long long bal = __ballot(ok);

        float cA = 0.0f, cB = 0.0f;
        if (bal != 0ull) {
            // Sentinels: +INF for min-side & fallback (auto-fail box tests),
            // -INF for max-side.
            const float pxl = ok ? px : INFINITY;
            const float pyl = ok ? py : INFINITY;
            const float pxh = ok ? px : -INFINITY;
            const float pyh = ok ? py : -INFINITY;

            // Exact f32 butterfly min/max per 32-lane half (xor masks <=16).
            float xlo = pxl, ylo = pyl, xhi = pxh, yhi = pyh;
            #pragma unroll
            for (int m = 16; m >= 1; m >>= 1) {
                xlo = fminf(xlo, __shfl_xor(xlo, m, 64));
                xhi = fmaxf(xhi, __shfl_xor(xhi, m, 64));
                ylo = fminf(ylo, __shfl_xor(ylo, m, 64));
                yhi = fmaxf(yhi, __shfl_xor(yhi, m, 64));
            }
            const float AxL = __int_as_float(__builtin_amdgcn_readlane(__float_as_int(xlo), 0));
            const float AxH = __int_as_float(__builtin_amdgcn_readlane(__float_as_int(xhi), 0));
            const float AyL = __int_as_float(__builtin_amdgcn_readlane(__float_as_int(ylo), 0));
            const float AyH = __int_as_float(__builtin_amdgcn_readlane(__float_as_int(yhi), 0));
            const float BxL = __int_as_float(__builtin_amdgcn_readlane(__float_as_int(xlo), 32));
            const float BxH = __int_as_float(__builtin_amdgcn_readlane(__float_as_int(xhi), 32));
            const float ByL = __int_as_float(__builtin_amdgcn_readlane(__float_as_int(ylo), 32));
            const float ByH = __int_as_float(__builtin_amdgcn_readlane(__float_as_int(yhi), 32));

            const bool anyA = ((unsigned)bal) != 0u;
            const bool anyB = (bal >> 32) != 0ull;

            const int ipx = __float_as_int(pxl);
            const int ipy = __float_as_int(pyl);

            // ---- pair A ----
            {
                bool hit = anyA && (AxL > ra.x) && (AxH < ra.z) && (AyL > ra.y) && (AyH < ra.w);
                const bool disj = !anyA || !(AxH > ra.x) || !(AxL < ra.z) || !(AyH > ra.y) || !(AyL < ra.w);
                if (__ballot(!hit && !disj) != 0ull) {
                    bool h = false;
                    #pragma unroll
                    for (int q = 0; q < 32; ++q) {
                        const float xd = __int_as_float(__builtin_amdgcn_readlane(ipx, q));
                        const float yd = __int_as_float(__builtin_amdgcn_readlane(ipy, q));
                        h = h || ((xd > ra.x) && (xd < ra.z) && (yd > ra.y) && (yd < ra.w));
                    }
                    hit = h;   // bit-exact (INF sentinels kill invalid depths)
                }
                cA = hit ? 1.0f : 0.0f;
            }
            // ---- pair B ----
            {
                bool hit = anyB && (BxL > rb.x) && (BxH < rb.z) && (ByL > rb.y) && (ByH < rb.w);
                const bool disj = !anyB || !(BxH > rb.x) || !(BxL < rb.z) || !(ByH > rb.y) || !(ByL < rb.w);
                if (__ballot(!hit && !disj) != 0ull) {
                    bool h = false;
                    #pragma unroll
                    for (int q = 0; q < 32; ++q) {
                        const float xd = __int_as_float(__builtin_amdgcn_readlane(ipx, q + 32));
                        const float yd = __int_as_float(__builtin_amdgcn_readlane(ipy, q + 32));
                        h = h || ((xd > rb.x) && (xd < rb.z) && (yd > rb.y) && (yd < rb.w));
                    }
                    hit = h;
                }
                cB = hit ? 1.0f : 0.0f;
            }
        }

        out_corr[(size_t)pA * P + lane] = cA;
        out_corr[(size_t)pB * P + lane] = cB;
    }
}

extern "C" void kernel_launch(void* const* d_in, const int* in_sizes, int n_in,
                              void* d_out, int out_size, void* d_ws, size_t ws_size,
                              hipStream_t stream) {
    const float* points = (const float*)d_in[0];   // 20000*3
    const float* trans  = (const float*)d_in[1];   // 6*6*4*4
    const float* rois   = (const float*)d_in[2];   // 6*64*4

    float* out      = (float*)d_out;
    float* out_xy   = out;                                   // N*V*ND*2
    float* out_mask = out + (size_t)N * V * ND * 2;          // N*V*ND
    float* out_corr = out_mask + (size_t)N * V * ND;         // N*V*P

    const int waves  = (N * V) / 8;      // 15000 waves, 8 pairs each (4 iters)
    const int blocks = (waves + 3) / 4;  // 3750 blocks, 4 waves each
    box_corr<<<blocks, 256, 0, stream>>>(points, trans, rois, out_xy, out_mask, out_corr);
}

// Round 9
// 97.518 us; speedup vs baseline: 1.0216x; 1.0216x over previous
//
#include <hip/hip_runtime.h>
#include <math.h>

constexpr int N  = 20000;
constexpr int V  = 6;
constexpr int P  = 64;
constexpr int ND = 32;
constexpr float W_   = 1600.0f;
constexpr float H_   = 928.0f;
constexpr float EPS_ = 1e-5f;

typedef float f32x2 __attribute__((ext_vector_type(2)));

// FINAL (= round-7 measured-best, 97.8us total / ~27us kernel).
// One wave per FOUR (n,v) pairs: 2 unrolled independent iterations x
// (lanes 0..31 = pair A depths, lanes 32..63 = pair B depths).
// Session ledger:
//  - R1 one-wave-per-pair baseline: kernel ~84us (VALU-issue bound, 61% busy)
//  - R2 2-pairs/wave + ctz valid-depth loop: ~52us
//  - R3 exact bbox prune (butterfly min/max + rare exact fallback): ~28us
//  - R5 f16 packed butterfly + NT stores: neutral (ambiguity band widened)
//  - R6 LDS-broadcast fallback: neutral (phase 2 not the bottleneck)
//  - R7 2x ILP unroll: -3us (latency exposure -> issue overlap)  << THIS
//  - R8 4x ILP unroll: +2us (scheduler/VGPR pressure) — reverted
// Remaining gap vs overlapped floors (~12us issue, ~12us write drain) is
// serial-chain latency exposure; all remaining levers cost out below the
// +-2us harness noise floor.
__global__ __launch_bounds__(256) void box_corr(
    const float* __restrict__ points,   // N x 3  [img_id, x, y]
    const float* __restrict__ trans,    // V x V x 4 x 4
    const float* __restrict__ rois,     // V x P x 4  [x1,y1,x2,y2]
    float* __restrict__ out_xy,         // N x V x ND x 2
    float* __restrict__ out_mask,       // N x V x ND
    float* __restrict__ out_corr)       // N x V x P
{
    const int tid  = (int)threadIdx.x;
    const int wid  = __builtin_amdgcn_readfirstlane(
                        (int)((blockIdx.x * 256u + tid) >> 6));
    const int lane = tid & 63;

    #pragma unroll
    for (int it = 0; it < 2; ++it) {
        const int gw = wid * 2 + it;           // < 60000 by grid construction

        const int pA = 2 * gw;
        const int pB = pA + 1;
        const int nA = pA / V, vA = pA - nA * V;
        const int nB = pB / V, vB = pB - nB * V;

        const float idA = points[nA * 3 + 0];
        const float xA  = points[nA * 3 + 1];
        const float yA  = points[nA * 3 + 2];
        const float idB = points[nB * 3 + 0];
        const float xB  = points[nB * 3 + 1];
        const float yB  = points[nB * 3 + 2];
        const int imgA = (int)idA;
        const int imgB = (int)idB;
        const int offA = (vA * V + imgA) * 16;
        const int offB = (vB * V + imgB) * 16;

        // Early ROI loads: independent of the matvec/divide chain (L1-hot).
        const float4 ra = ((const float4*)rois)[vA * P + lane];
        const float4 rb = ((const float4*)rois)[vB * P + lane];

        const bool hiHalf = lane >= 32;
        const int  dl     = lane & 31;
        const float x   = hiHalf ? xB : xA;
        const float y   = hiHalf ? yB : yA;
        const int   off = hiHalf ? offB : offA;

        // depths[k] = 0.5 + bin*k*(k+1), left-assoc f32 (matches jnp)
        const float k   = (float)dl;
        const float bin = (float)(69.5 / 1056.0);
        const float d   = __fadd_rn(0.5f, __fmul_rn(__fmul_rn(bin, k), __fadd_rn(k, 1.0f)));

        const float p0 = __fmul_rn(x, d);
        const float p1 = __fmul_rn(y, d);

        const float* T = trans + off;
        const float4 t0 = *(const float4*)(T + 0);
        const float4 t1 = *(const float4*)(T + 4);
        const float4 t2 = *(const float4*)(T + 8);
        // no FMA contraction: match numpy einsum's mul+add sequence
        const float r0 = __fadd_rn(__fadd_rn(__fadd_rn(__fmul_rn(t0.x, p0), __fmul_rn(t0.y, p1)), __fmul_rn(t0.z, d)), t0.w);
        const float r1 = __fadd_rn(__fadd_rn(__fadd_rn(__fmul_rn(t1.x, p0), __fmul_rn(t1.y, p1)), __fmul_rn(t1.z, d)), t1.w);
        const float r2 = __fadd_rn(__fadd_rn(__fadd_rn(__fmul_rn(t2.x, p0), __fmul_rn(t2.y, p1)), __fmul_rn(t2.z, d)), t2.w);

        const float zc = fmaxf(r2, EPS_);
        const float px = r0 / zc;   // IEEE divide — booleans must be exact
        const float py = r1 / zc;
        const bool  ok = (r2 > EPS_) && (px >= 0.0f) && (px < W_) && (py >= 0.0f) && (py < H_);

        // Coalesced streaming stores (gw*64+lane contiguous).
        const size_t base = (size_t)gw * 64 + lane;
        ((f32x2*)out_xy)[base] = (f32x2){ px, py };
        out_mask[base] = ok ? 1.0f : 0.0f;

        const unsigned long long bal = __ballot(ok);

        float cA = 0.0f, cB = 0.0f;
        if (bal != 0ull) {
            // Sentinels: +INF for min-side & fallback (auto-fail box tests),
            // -INF for max-side.
            const float pxl = ok ? px : INFINITY;
            const float pyl = ok ? py : INFINITY;
            const float pxh = ok ? px : -INFINITY;
            const float pyh = ok ? py : -INFINITY;

            // Exact f32 butterfly min/max per 32-lane half (xor masks <=16).
            float xlo = pxl, ylo = pyl, xhi = pxh, yhi = pyh;
            #pragma unroll
            for (int m = 16; m >= 1; m >>= 1) {
                xlo = fminf(xlo, __shfl_xor(xlo, m, 64));
                xhi = fmaxf(xhi, __shfl_xor(xhi, m, 64));
                ylo = fminf(ylo, __shfl_xor(ylo, m, 64));
                yhi = fmaxf(yhi, __shfl_xor(yhi, m, 64));
            }
            const float AxL = __int_as_float(__builtin_amdgcn_readlane(__float_as_int(xlo), 0));
            const float AxH = __int_as_float(__builtin_amdgcn_readlane(__float_as_int(xhi), 0));
            const float AyL = __int_as_float(__builtin_amdgcn_readlane(__float_as_int(ylo), 0));
            const float AyH = __int_as_float(__builtin_amdgcn_readlane(__float_as_int(yhi), 0));
            const float BxL = __int_as_float(__builtin_amdgcn_readlane(__float_as_int(xlo), 32));
            const float BxH = __int_as_float(__builtin_amdgcn_readlane(__float_as_int(xhi), 32));
            const float ByL = __int_as_float(__builtin_amdgcn_readlane(__float_as_int(ylo), 32));
            const float ByH = __int_as_float(__builtin_amdgcn_readlane(__float_as_int(yhi), 32));

            const bool anyA = ((unsigned)bal) != 0u;
            const bool anyB = (bal >> 32) != 0ull;

            const int ipx = __float_as_int(pxl);
            const int ipy = __float_as_int(pyl);

            // ---- pair A ----
            {
                bool hit = anyA && (AxL > ra.x) && (AxH < ra.z) && (AyL > ra.y) && (AyH < ra.w);
                const bool disj = !anyA || !(AxH > ra.x) || !(AxL < ra.z) || !(AyH > ra.y) || !(AyL < ra.w);
                if (__ballot(!hit && !disj) != 0ull) {
                    bool h = false;
                    #pragma unroll
                    for (int q = 0; q < 32; ++q) {
                        const float xd = __int_as_float(__builtin_amdgcn_readlane(ipx, q));
                        const float yd = __int_as_float(__builtin_amdgcn_readlane(ipy, q));
                        h = h || ((xd > ra.x) && (xd < ra.z) && (yd > ra.y) && (yd < ra.w));
                    }
                    hit = h;   // bit-exact (INF sentinels kill invalid depths)
                }
                cA = hit ? 1.0f : 0.0f;
            }
            // ---- pair B ----
            {
                bool hit = anyB && (BxL > rb.x) && (BxH < rb.z) && (ByL > rb.y) && (ByH < rb.w);
                const bool disj = !anyB || !(BxH > rb.x) || !(BxL < rb.z) || !(ByH > rb.y) || !(ByL < rb.w);
                if (__ballot(!hit && !disj) != 0ull) {
                    bool h = false;
                    #pragma unroll
                    for (int q = 0; q < 32; ++q) {
                        const float xd = __int_as_float(__builtin_amdgcn_readlane(ipx, q + 32));
                        const float yd = __int_as_float(__builtin_amdgcn_readlane(ipy, q + 32));
                        h = h || ((xd > rb.x) && (xd < rb.z) && (yd > rb.y) && (yd < rb.w));
                    }
                    hit = h;
                }
                cB = hit ? 1.0f : 0.0f;
            }
        }

        out_corr[(size_t)pA * P + lane] = cA;
        out_corr[(size_t)pB * P + lane] = cB;
    }
}

extern "C" void kernel_launch(void* const* d_in, const int* in_sizes, int n_in,
                              void* d_out, int out_size, void* d_ws, size_t ws_size,
                              hipStream_t stream) {
    const float* points = (const float*)d_in[0];   // 20000*3
    const float* trans  = (const float*)d_in[1];   // 6*6*4*4
    const float* rois   = (const float*)d_in[2];   // 6*64*4

    float* out      = (float*)d_out;
    float* out_xy   = out;                                   // N*V*ND*2
    float* out_mask = out + (size_t)N * V * ND * 2;          // N*V*ND
    float* out_corr = out_mask + (size_t)N * V * ND;         // N*V*P

    const int waves  = (N * V) / 4;      // 30000 waves, 4 pairs each (2 iters)
    const int blocks = (waves + 3) / 4;  // 7500 blocks, 4 waves each
    box_corr<<<blocks, 256, 0, stream>>>(points, trans, rois, out_xy, out_mask, out_corr);
}